// Round 1
// baseline (1199.052 us; speedup 1.0000x reference)
//
#include <hip/hip_runtime.h>

typedef unsigned short ushort;
typedef unsigned int uint;

typedef __attribute__((ext_vector_type(8))) short short8;     // bf16x8 MFMA frag
typedef __attribute__((ext_vector_type(8))) unsigned short ushort8;
typedef __attribute__((ext_vector_type(4))) unsigned short ushort4v;
typedef __attribute__((ext_vector_type(4))) float f32x4;

#define DEV static __device__ __forceinline__

DEV ushort f2b(float f){
  union { float f; uint u; } v; v.f = f;
  uint u = v.u;
  u += 0x7fffu + ((u >> 16) & 1u);   // round-to-nearest-even
  return (ushort)(u >> 16);
}
DEV float b2f(ushort h){
  union { uint u; float f; } v; v.u = ((uint)h) << 16;
  return v.f;
}

constexpr int Bc = 2, Tc = 2048, Dc = 1024, Hc = 16, DHc = 64, NBc = 32;
constexpr int Rc = Bc * Tc;   // 4096 rows
constexpr int D4c = 4 * Dc;   // 4096

// ---------------- weight transpose + f32->bf16: in (K,N) -> out (N,K) ----------------
__global__ __launch_bounds__(256) void k_transcvt(const float* __restrict__ in,
                                                  ushort* __restrict__ out, int K, int N){
  __shared__ float tile[32][33];
  int n0 = blockIdx.x * 32, k0 = blockIdx.y * 32;
  int c = threadIdx.x & 31, r0 = threadIdx.x >> 5;
#pragma unroll
  for (int i = 0; i < 4; i++){
    int k = r0 + i * 8;
    tile[k][c] = in[(size_t)(k0 + k) * N + n0 + c];
  }
  __syncthreads();
#pragma unroll
  for (int i = 0; i < 4; i++){
    int n = r0 + i * 8;
    out[(size_t)(n0 + n) * K + k0 + c] = f2b(tile[c][n]);
  }
}

// ---------------- LayerNorm: f32 (R,D) -> bf16 (R,D) ----------------
__global__ __launch_bounds__(256) void k_ln(const float* __restrict__ x, const float* __restrict__ g,
                                            const float* __restrict__ bb, ushort* __restrict__ out){
  int row = blockIdx.x, tid = threadIdx.x;
  const f32x4* xr = (const f32x4*)(x + (size_t)row * Dc);
  f32x4 v = xr[tid];
  float s  = v.x + v.y + v.z + v.w;
  float ss = v.x*v.x + v.y*v.y + v.z*v.z + v.w*v.w;
#pragma unroll
  for (int off = 32; off > 0; off >>= 1){
    s  += __shfl_xor(s,  off, 64);
    ss += __shfl_xor(ss, off, 64);
  }
  __shared__ float red[2][4];
  int w = tid >> 6;
  if ((tid & 63) == 0){ red[0][w] = s; red[1][w] = ss; }
  __syncthreads();
  s  = red[0][0] + red[0][1] + red[0][2] + red[0][3];
  ss = red[1][0] + red[1][1] + red[1][2] + red[1][3];
  float mu  = s * (1.f / Dc);
  float var = ss * (1.f / Dc) - mu * mu;
  float rs  = rsqrtf(var + 1e-5f);
  f32x4 gv = ((const f32x4*)g)[tid];
  f32x4 bv = ((const f32x4*)bb)[tid];
  ushort4v o;
  o.x = f2b((v.x - mu) * rs * gv.x + bv.x);
  o.y = f2b((v.y - mu) * rs * gv.y + bv.y);
  o.z = f2b((v.z - mu) * rs * gv.z + bv.z);
  o.w = f2b((v.w - mu) * rs * gv.w + bv.w);
  ((ushort4v*)(out + (size_t)row * Dc))[tid] = o;
}

// ---------------- bf16 MFMA GEMM: C = A(MxK) * Bt(NxK)^T + bias [+resid] [gelu] ----------------
#define GLDS(src, dst) __builtin_amdgcn_global_load_lds( \
    (const __attribute__((address_space(1))) void*)(src), \
    (__attribute__((address_space(3))) void*)(dst), 16, 0, 0)

template<int OUT_BF16, int ACT_GELU, int HAS_RES>
__global__ __launch_bounds__(256) void k_gemm(const ushort* __restrict__ A, const ushort* __restrict__ Bt,
                                              const float* __restrict__ bias, const float* __restrict__ resid,
                                              void* __restrict__ Cout, int M, int N, int K){
  // 128x128 tile, BK=64, 4 waves in 2x2, 64x64 per wave (4x4 frags of 16x16x32 MFMA).
  // LDS rows are 64 bf16 = 128B; 16B granules XOR-swizzled by (row&7) to avoid the
  // 128B-stride bank conflict; global_load_lds writes linearly so the SOURCE address
  // carries the inverse swizzle (both-sides rule).
  __shared__ ushort As[128 * 64];
  __shared__ ushort Bs[128 * 64];
  const int tid = threadIdx.x;
  const int m0 = blockIdx.y * 128, n0 = blockIdx.x * 128;
  const int w = tid >> 6, lane = tid & 63;
  const int wr = w >> 1, wc = w & 1;
  const int la15 = lane & 15, lg = lane >> 4, l7 = lane & 7;
  const int rloc = lane >> 3, gsrc = (lane & 7) ^ rloc;

  f32x4 acc[4][4];
#pragma unroll
  for (int i = 0; i < 4; i++)
#pragma unroll
    for (int j = 0; j < 4; j++) acc[i][j] = f32x4{0.f, 0.f, 0.f, 0.f};

  const int arow = wr * 64 + la15;
  const int brow = wc * 64 + la15;

  for (int k0 = 0; k0 < K; k0 += 64){
    __syncthreads();
#pragma unroll
    for (int i = 0; i < 4; i++){
      int chunk = w * 4 + i;                      // 8 rows per chunk
      const ushort* sa = A  + (size_t)(m0 + chunk * 8 + rloc) * K + k0 + gsrc * 8;
      const ushort* sb = Bt + (size_t)(n0 + chunk * 8 + rloc) * K + k0 + gsrc * 8;
      GLDS(sa, &As[chunk * 512]);
      GLDS(sb, &Bs[chunk * 512]);
    }
    __syncthreads();
#pragma unroll
    for (int ks = 0; ks < 2; ks++){
      const int gs = (ks * 4 + lg) ^ l7;          // swizzled granule (row&7 == l7 for all frags)
      short8 aF[4], bF[4];
#pragma unroll
      for (int mi = 0; mi < 4; mi++) aF[mi] = *(const short8*)&As[(arow + mi * 16) * 64 + gs * 8];
#pragma unroll
      for (int ni = 0; ni < 4; ni++) bF[ni] = *(const short8*)&Bs[(brow + ni * 16) * 64 + gs * 8];
#pragma unroll
      for (int mi = 0; mi < 4; mi++)
#pragma unroll
        for (int ni = 0; ni < 4; ni++)
          acc[mi][ni] = __builtin_amdgcn_mfma_f32_16x16x32_bf16(aF[mi], bF[ni], acc[mi][ni], 0, 0, 0);
    }
  }

#pragma unroll
  for (int mi = 0; mi < 4; mi++){
#pragma unroll
    for (int ni = 0; ni < 4; ni++){
      int cc = n0 + wc * 64 + ni * 16 + la15;
      float bv = bias[cc];
      f32x4 a4 = acc[mi][ni];
#pragma unroll
      for (int r = 0; r < 4; r++){
        int rr = m0 + wr * 64 + mi * 16 + lg * 4 + r;
        float v = a4[r] + bv;
        if (HAS_RES)  v += resid[(size_t)rr * N + cc];
        if (ACT_GELU) v = 0.5f * v * (1.f + erff(v * 0.70710678118654752f));
        if (OUT_BF16) ((ushort*)Cout)[(size_t)rr * N + cc] = f2b(v);
        else          ((float*)Cout)[(size_t)rr * N + cc] = v;
      }
    }
  }
}

// ---------------- RoPE in-place on bf16 Q and K ----------------
__global__ __launch_bounds__(256) void k_rope(ushort* __restrict__ q, ushort* __restrict__ k,
                                              const float* __restrict__ ca, const float* __restrict__ sa){
  int idx = blockIdx.x * 256 + threadIdx.x;       // B*T*H*NB = 2^21
  int nb = idx & 31;
  int hh = (idx >> 5) & 15;
  int t  = (idx >> 9) & 2047;
  int b  = idx >> 20;
  size_t base = (size_t)(b * Tc + t) * Dc + hh * DHc + nb * 2;
  int ai = ((b * Hc + hh) * Tc + t) * NBc + nb;
  float c = ca[ai], s = sa[ai];
  uint qu = *(const uint*)(q + base);
  float q1 = b2f((ushort)(qu & 0xffff)), q2 = b2f((ushort)(qu >> 16));
  uint qo = (uint)f2b(q1 * c - q2 * s) | ((uint)f2b(q1 * s + q2 * c) << 16);
  *(uint*)(q + base) = qo;
  uint ku = *(const uint*)(k + base);
  float k1 = b2f((ushort)(ku & 0xffff)), k2 = b2f((ushort)(ku >> 16));
  uint ko = (uint)f2b(k1 * c - k2 * s) | ((uint)f2b(k1 * s + k2 * c) << 16);
  *(uint*)(k + base) = ko;
}

// ---------------- inv scale: 1 / (8 * (1 + mean_nb sigma)) laid out (B,H,T) ----------------
__global__ __launch_bounds__(256) void k_iscale(const float* __restrict__ sigma, float* __restrict__ isc){
  int idx = blockIdx.x * 256 + threadIdx.x;       // B*T*H = 65536, idx = (b*T+t)*H + h
  int hh = idx & 15;
  int t  = (idx >> 4) & 2047;
  int b  = idx >> 15;
  const f32x4* sp = (const f32x4*)(sigma + (size_t)idx * NBc);
  float s = 0.f;
#pragma unroll
  for (int i = 0; i < 8; i++){ f32x4 v = sp[i]; s += v.x + v.y + v.z + v.w; }
  isc[(b * Hc + hh) * Tc + t] = 1.f / (8.f * (1.f + s * (1.f / NBc)));
}

// ---------------- causal flash attention (vector f32), 64 q-rows/block ----------------
__global__ __launch_bounds__(256) void k_attn(const ushort* __restrict__ qb, const ushort* __restrict__ kb,
                                              const ushort* __restrict__ vb, const float* __restrict__ isc,
                                              ushort* __restrict__ ao){
  __shared__ float Ks[64][68];   // pad 64->68 to spread staging-write banks
  __shared__ float Vs[64][68];
  int bh = blockIdx.y;
  int b = bh >> 4, hh = bh & 15;
  int q0 = blockIdx.x * 64;
  int tid = threadIdx.x;
  int qr = tid >> 2, quad = tid & 3;              // 4 lanes per q-row, 16 dh each
  int q = q0 + qr;
  size_t qoff = (size_t)(b * Tc + q) * Dc + hh * DHc + quad * 16;

  float qreg[16];
  {
    ushort8 u0 = *(const ushort8*)(qb + qoff);
    ushort8 u1 = *(const ushort8*)(qb + qoff + 8);
#pragma unroll
    for (int i = 0; i < 8; i++){ qreg[i] = b2f(u0[i]); qreg[8 + i] = b2f(u1[i]); }
  }
  float sc_i = isc[bh * Tc + q];
  float m = -1e30f, lsum = 0.f;
  float O[16];
#pragma unroll
  for (int i = 0; i < 16; i++) O[i] = 0.f;

  for (int kt = 0; kt <= q0; kt += 64){
    __syncthreads();
#pragma unroll
    for (int i2 = 0; i2 < 2; i2++){
      int e = tid + i2 * 256;
      int r = e >> 3, gg = e & 7;
      size_t goff = (size_t)(b * Tc + kt + r) * Dc + hh * DHc + gg * 8;
      ushort8 ku = *(const ushort8*)(kb + goff);
      ushort8 vu = *(const ushort8*)(vb + goff);
#pragma unroll
      for (int j = 0; j < 8; j++){ Ks[r][gg * 8 + j] = b2f(ku[j]); Vs[r][gg * 8 + j] = b2f(vu[j]); }
    }
    __syncthreads();
    int jmax = q - kt + 1; if (jmax > 64) jmax = 64;
    for (int j = 0; j < jmax; j++){
      const float* kr = &Ks[j][quad * 16];
      float s = 0.f;
#pragma unroll
      for (int i = 0; i < 16; i++) s += qreg[i] * kr[i];
      s += __shfl_xor(s, 1, 64);
      s += __shfl_xor(s, 2, 64);
      s *= sc_i;
      float mn  = fmaxf(m, s);
      float esc = __expf(m - mn);
      float p   = __expf(s - mn);
      lsum = lsum * esc + p;
      const float* vr = &Vs[j][quad * 16];
#pragma unroll
      for (int i = 0; i < 16; i++) O[i] = O[i] * esc + p * vr[i];
      m = mn;
    }
  }
  float inv = 1.f / lsum;
#pragma unroll
  for (int i = 0; i < 16; i++) ao[qoff + i] = f2b(O[i] * inv);
}

// ---------------- host ----------------
extern "C" void kernel_launch(void* const* d_in, const int* in_sizes, int n_in,
                              void* d_out, int out_size, void* d_ws, size_t ws_size,
                              hipStream_t stream){
  (void)in_sizes; (void)n_in; (void)out_size; (void)ws_size;
  const float* x    = (const float*)d_in[0];
  const float* cosa = (const float*)d_in[1];
  const float* sina = (const float*)d_in[2];
  const float* sigma= (const float*)d_in[3];
  // d_in[4] = causal_mask (unused; causality handled analytically)
  const float* ln1g = (const float*)d_in[5];
  const float* ln1b = (const float*)d_in[6];
  const float* wq   = (const float*)d_in[7];
  const float* bq   = (const float*)d_in[8];
  const float* wk   = (const float*)d_in[9];
  const float* bk   = (const float*)d_in[10];
  const float* wv   = (const float*)d_in[11];
  const float* bv   = (const float*)d_in[12];
  const float* wo   = (const float*)d_in[13];
  const float* bo   = (const float*)d_in[14];
  const float* ln2g = (const float*)d_in[15];
  const float* ln2b = (const float*)d_in[16];
  const float* w1   = (const float*)d_in[17];
  const float* b1   = (const float*)d_in[18];
  const float* w2   = (const float*)d_in[19];
  const float* b2   = (const float*)d_in[20];
  float* out = (float*)d_out;

  char* ws = (char*)d_ws;
  constexpr size_t MB = 1024 * 1024;
  // layout (80.25 MB total):
  ushort* wqT  = (ushort*)(ws +  0 * MB);  // 2MB  (D x D bf16, transposed)
  ushort* wkT  = (ushort*)(ws +  2 * MB);
  ushort* wvT  = (ushort*)(ws +  4 * MB);
  ushort* woT  = (ushort*)(ws +  6 * MB);
  ushort* w1T  = (ushort*)(ws +  8 * MB);  // 8MB  (4D x D)
  ushort* w2T  = (ushort*)(ws + 16 * MB);  // 8MB  (D x 4D)
  ushort* hb   = (ushort*)(ws + 24 * MB);  // 8MB  h (bf16); reused for h2 after attention
  ushort* qbuf = (ushort*)(ws + 32 * MB);  // 8MB; [32..64)MB reused as gelu-out (32MB) in FFN
  ushort* kbuf = (ushort*)(ws + 40 * MB);
  ushort* vbuf = (ushort*)(ws + 48 * MB);
  ushort* aob  = (ushort*)(ws + 56 * MB);
  float*  x2   = (float*)(ws + 64 * MB);   // 16MB
  float*  iscp = (float*)(ws + 80 * MB);   // 256KB
  ushort* g1b  = qbuf;                     // 32MB alias over qbuf/kbuf/vbuf/aob (dead by then)

  // 1. weight transpose + convert
  k_transcvt<<<dim3(Dc / 32, Dc / 32), 256, 0, stream>>>(wq, wqT, Dc, Dc);
  k_transcvt<<<dim3(Dc / 32, Dc / 32), 256, 0, stream>>>(wk, wkT, Dc, Dc);
  k_transcvt<<<dim3(Dc / 32, Dc / 32), 256, 0, stream>>>(wv, wvT, Dc, Dc);
  k_transcvt<<<dim3(Dc / 32, Dc / 32), 256, 0, stream>>>(wo, woT, Dc, Dc);
  k_transcvt<<<dim3(D4c / 32, Dc / 32), 256, 0, stream>>>(w1, w1T, Dc, D4c);
  k_transcvt<<<dim3(Dc / 32, D4c / 32), 256, 0, stream>>>(w2, w2T, D4c, Dc);
  // 2. LN1
  k_ln<<<Rc, 256, 0, stream>>>(x, ln1g, ln1b, hb);
  // 3. QKV projections (bf16 out)
  k_gemm<1, 0, 0><<<dim3(Dc / 128, Rc / 128), 256, 0, stream>>>(hb, wqT, bq, nullptr, qbuf, Rc, Dc, Dc);
  k_gemm<1, 0, 0><<<dim3(Dc / 128, Rc / 128), 256, 0, stream>>>(hb, wkT, bk, nullptr, kbuf, Rc, Dc, Dc);
  k_gemm<1, 0, 0><<<dim3(Dc / 128, Rc / 128), 256, 0, stream>>>(hb, wvT, bv, nullptr, vbuf, Rc, Dc, Dc);
  // 4. RoPE in-place on Q,K
  k_rope<<<(Bc * Tc * Hc * NBc) / 256, 256, 0, stream>>>(qbuf, kbuf, cosa, sina);
  // 5. temperature -> inv scale
  k_iscale<<<(Bc * Tc * Hc) / 256, 256, 0, stream>>>(sigma, iscp);
  // 6. causal attention
  k_attn<<<dim3(Tc / 64, Bc * Hc), 256, 0, stream>>>(qbuf, kbuf, vbuf, iscp, aob);
  // 7. out-proj + residual (f32 out)
  k_gemm<0, 0, 1><<<dim3(Dc / 128, Rc / 128), 256, 0, stream>>>(aob, woT, bo, x, x2, Rc, Dc, Dc);
  // 8. LN2
  k_ln<<<Rc, 256, 0, stream>>>(x2, ln2g, ln2b, hb);
  // 9. FFN1 + exact GELU (bf16 out)
  k_gemm<1, 1, 0><<<dim3(D4c / 128, Rc / 128), 256, 0, stream>>>(hb, w1T, b1, nullptr, g1b, Rc, D4c, Dc);
  // 10. FFN2 + residual -> final output (f32)
  k_gemm<0, 0, 1><<<dim3(Dc / 128, Rc / 128), 256, 0, stream>>>(g1b, w2T, b2, x2, out, Rc, Dc, D4c);
}

// Round 2
// 404.396 us; speedup vs baseline: 2.9650x; 2.9650x over previous
//
#include <hip/hip_runtime.h>

typedef unsigned short ushort;
typedef unsigned int uint;

typedef __attribute__((ext_vector_type(8))) short short8;     // bf16x8 MFMA frag
typedef __attribute__((ext_vector_type(8))) unsigned short ushort8;
typedef __attribute__((ext_vector_type(4))) unsigned short ushort4v;
typedef __attribute__((ext_vector_type(4))) float f32x4;
typedef __attribute__((ext_vector_type(4))) uint uint4v;

#define DEV static __device__ __forceinline__

DEV ushort f2b(float f){
  union { float f; uint u; } v; v.f = f;
  uint u = v.u;
  u += 0x7fffu + ((u >> 16) & 1u);   // round-to-nearest-even
  return (ushort)(u >> 16);
}
DEV float b2f(ushort h){
  union { uint u; float f; } v; v.u = ((uint)h) << 16;
  return v.f;
}

constexpr int Bc = 2, Tc = 2048, Dc = 1024, Hc = 16, DHc = 64, NBc = 32;
constexpr int Rc = Bc * Tc;   // 4096 rows
constexpr int D4c = 4 * Dc;   // 4096

// ---------------- weight transpose + f32->bf16: in (K,N) -> out (N,K) ----------------
__global__ __launch_bounds__(256) void k_transcvt(const float* __restrict__ in,
                                                  ushort* __restrict__ out, int K, int N){
  __shared__ float tile[32][33];
  int n0 = blockIdx.x * 32, k0 = blockIdx.y * 32;
  int c = threadIdx.x & 31, r0 = threadIdx.x >> 5;
#pragma unroll
  for (int i = 0; i < 4; i++){
    int k = r0 + i * 8;
    tile[k][c] = in[(size_t)(k0 + k) * N + n0 + c];
  }
  __syncthreads();
#pragma unroll
  for (int i = 0; i < 4; i++){
    int n = r0 + i * 8;
    out[(size_t)(n0 + n) * K + k0 + c] = f2b(tile[c][n]);
  }
}

// ---------------- LayerNorm: f32 (R,D) -> bf16 (R,D) ----------------
__global__ __launch_bounds__(256) void k_ln(const float* __restrict__ x, const float* __restrict__ g,
                                            const float* __restrict__ bb, ushort* __restrict__ out){
  int row = blockIdx.x, tid = threadIdx.x;
  const f32x4* xr = (const f32x4*)(x + (size_t)row * Dc);
  f32x4 v = xr[tid];
  float s  = v.x + v.y + v.z + v.w;
  float ss = v.x*v.x + v.y*v.y + v.z*v.z + v.w*v.w;
#pragma unroll
  for (int off = 32; off > 0; off >>= 1){
    s  += __shfl_xor(s,  off, 64);
    ss += __shfl_xor(ss, off, 64);
  }
  __shared__ float red[2][4];
  int w = tid >> 6;
  if ((tid & 63) == 0){ red[0][w] = s; red[1][w] = ss; }
  __syncthreads();
  s  = red[0][0] + red[0][1] + red[0][2] + red[0][3];
  ss = red[1][0] + red[1][1] + red[1][2] + red[1][3];
  float mu  = s * (1.f / Dc);
  float var = ss * (1.f / Dc) - mu * mu;
  float rs  = rsqrtf(var + 1e-5f);
  f32x4 gv = ((const f32x4*)g)[tid];
  f32x4 bv = ((const f32x4*)bb)[tid];
  ushort4v o;
  o.x = f2b((v.x - mu) * rs * gv.x + bv.x);
  o.y = f2b((v.y - mu) * rs * gv.y + bv.y);
  o.z = f2b((v.z - mu) * rs * gv.z + bv.z);
  o.w = f2b((v.w - mu) * rs * gv.w + bv.w);
  ((ushort4v*)(out + (size_t)row * Dc))[tid] = o;
}

// ---------------- bf16 MFMA GEMM: C = A(MxK) * Bt(NxK)^T + bias [+resid] [gelu] ----------------
#define GLDS(src, dst) __builtin_amdgcn_global_load_lds( \
    (const __attribute__((address_space(1))) void*)(src), \
    (__attribute__((address_space(3))) void*)(dst), 16, 0, 0)

template<int OUT_BF16, int ACT_GELU, int HAS_RES>
__global__ __launch_bounds__(256) void k_gemm(const ushort* __restrict__ A, const ushort* __restrict__ Bt,
                                              const float* __restrict__ bias, const float* __restrict__ resid,
                                              void* __restrict__ Cout, int M, int N, int K){
  // 128x128 tile, BK=64, 4 waves in 2x2, 64x64 per wave (4x4 frags of 16x16x32 MFMA).
  __shared__ ushort As[128 * 64];
  __shared__ ushort Bs[128 * 64];
  const int tid = threadIdx.x;
  const int m0 = blockIdx.y * 128, n0 = blockIdx.x * 128;
  const int w = tid >> 6, lane = tid & 63;
  const int wr = w >> 1, wc = w & 1;
  const int la15 = lane & 15, lg = lane >> 4, l7 = lane & 7;
  const int rloc = lane >> 3, gsrc = (lane & 7) ^ rloc;

  f32x4 acc[4][4];
#pragma unroll
  for (int i = 0; i < 4; i++)
#pragma unroll
    for (int j = 0; j < 4; j++) acc[i][j] = f32x4{0.f, 0.f, 0.f, 0.f};

  const int arow = wr * 64 + la15;
  const int brow = wc * 64 + la15;

  for (int k0 = 0; k0 < K; k0 += 64){
    __syncthreads();
#pragma unroll
    for (int i = 0; i < 4; i++){
      int chunk = w * 4 + i;                      // 8 rows per chunk
      const ushort* sa = A  + (size_t)(m0 + chunk * 8 + rloc) * K + k0 + gsrc * 8;
      const ushort* sb = Bt + (size_t)(n0 + chunk * 8 + rloc) * K + k0 + gsrc * 8;
      GLDS(sa, &As[chunk * 512]);
      GLDS(sb, &Bs[chunk * 512]);
    }
    __syncthreads();
#pragma unroll
    for (int ks = 0; ks < 2; ks++){
      const int gs = (ks * 4 + lg) ^ l7;          // swizzled granule
      short8 aF[4], bF[4];
#pragma unroll
      for (int mi = 0; mi < 4; mi++) aF[mi] = *(const short8*)&As[(arow + mi * 16) * 64 + gs * 8];
#pragma unroll
      for (int ni = 0; ni < 4; ni++) bF[ni] = *(const short8*)&Bs[(brow + ni * 16) * 64 + gs * 8];
#pragma unroll
      for (int mi = 0; mi < 4; mi++)
#pragma unroll
        for (int ni = 0; ni < 4; ni++)
          acc[mi][ni] = __builtin_amdgcn_mfma_f32_16x16x32_bf16(aF[mi], bF[ni], acc[mi][ni], 0, 0, 0);
    }
  }

#pragma unroll
  for (int mi = 0; mi < 4; mi++){
#pragma unroll
    for (int ni = 0; ni < 4; ni++){
      int cc = n0 + wc * 64 + ni * 16 + la15;
      float bv = bias[cc];
      f32x4 a4 = acc[mi][ni];
#pragma unroll
      for (int r = 0; r < 4; r++){
        int rr = m0 + wr * 64 + mi * 16 + lg * 4 + r;
        float v = a4[r] + bv;
        if (HAS_RES)  v += resid[(size_t)rr * N + cc];
        if (ACT_GELU) v = 0.5f * v * (1.f + erff(v * 0.70710678118654752f));
        if (OUT_BF16) ((ushort*)Cout)[(size_t)rr * N + cc] = f2b(v);
        else          ((float*)Cout)[(size_t)rr * N + cc] = v;
      }
    }
  }
}

// ---------------- RoPE in-place on bf16 Q and K ----------------
__global__ __launch_bounds__(256) void k_rope(ushort* __restrict__ q, ushort* __restrict__ k,
                                              const float* __restrict__ ca, const float* __restrict__ sa){
  int idx = blockIdx.x * 256 + threadIdx.x;       // B*T*H*NB = 2^21
  int nb = idx & 31;
  int hh = (idx >> 5) & 15;
  int t  = (idx >> 9) & 2047;
  int b  = idx >> 20;
  size_t base = (size_t)(b * Tc + t) * Dc + hh * DHc + nb * 2;
  int ai = ((b * Hc + hh) * Tc + t) * NBc + nb;
  float c = ca[ai], s = sa[ai];
  uint qu = *(const uint*)(q + base);
  float q1 = b2f((ushort)(qu & 0xffff)), q2 = b2f((ushort)(qu >> 16));
  uint qo = (uint)f2b(q1 * c - q2 * s) | ((uint)f2b(q1 * s + q2 * c) << 16);
  *(uint*)(q + base) = qo;
  uint ku = *(const uint*)(k + base);
  float k1 = b2f((ushort)(ku & 0xffff)), k2 = b2f((ushort)(ku >> 16));
  uint ko = (uint)f2b(k1 * c - k2 * s) | ((uint)f2b(k1 * s + k2 * c) << 16);
  *(uint*)(k + base) = ko;
}

// ---------------- inv scale: 1 / (8 * (1 + mean_nb sigma)) laid out (B,H,T) ----------------
__global__ __launch_bounds__(256) void k_iscale(const float* __restrict__ sigma, float* __restrict__ isc){
  int idx = blockIdx.x * 256 + threadIdx.x;       // B*T*H = 65536, idx = (b*T+t)*H + h
  int hh = idx & 15;
  int t  = (idx >> 4) & 2047;
  int b  = idx >> 15;
  const f32x4* sp = (const f32x4*)(sigma + (size_t)idx * NBc);
  float s = 0.f;
#pragma unroll
  for (int i = 0; i < 8; i++){ f32x4 v = sp[i]; s += v.x + v.y + v.z + v.w; }
  isc[(b * Hc + hh) * Tc + t] = 1.f / (8.f * (1.f + s * (1.f / NBc)));
}

// ---------------- MFMA causal flash attention ----------------
// Block: 4 waves x 32 q-rows = 128 q-rows per (b,h). KVBLK = 64.
// Swapped QK^T:  S^T[k][q] = mfma(A=K, B=Q)  -> lane: q = lane&15, k = (lane>>4)*4+reg (+16*tile)
// Swapped PV:    O^T[d][q] = mfma(A=V^T, B=P^T) accumulated in-register.
// K: LDS row-major [64][64], granule XOR-swizzle via pre-swizzled global src (GLDS).
// V: LDS transposed [64 d][64 k], reg-staged with swizzled writes (both-sides).
// P^T redistribution to B-operand fragments: 2x shfl + select, no LDS round-trip.
__global__ __launch_bounds__(256) void k_attn_mfma(const ushort* __restrict__ qb, const ushort* __restrict__ kb,
                                                   const ushort* __restrict__ vb, const float* __restrict__ isc,
                                                   ushort* __restrict__ ao){
  __shared__ ushort smem[8704];        // 17408 B: K[0,8K) + Vt[8K,16K); epilogue Os[0,17408)
  ushort* Ks = smem;
  ushort* Vt = smem + 4096;
  const int tid = threadIdx.x;
  const int wq = tid >> 6, lane = tid & 63;
  const int la15 = lane & 15, lg = lane >> 4, l7 = lane & 7;
  const int bh = blockIdx.y, b = bh >> 4, h = bh & 15;
  const int qi = 15 - blockIdx.x;      // reversed: longest blocks first
  const int q0 = qi * 128;
  const int q0w = q0 + wq * 32;
  const float NINF = -__builtin_inff();

  // Q fragments + per-row inv temperature scale
  short8 qf[2][2];
  float iscv[2];
#pragma unroll
  for (int sub = 0; sub < 2; sub++){
    int qg = q0w + sub * 16 + la15;
    size_t rb = (size_t)(b * Tc + qg) * Dc + h * DHc;
#pragma unroll
    for (int ds = 0; ds < 2; ds++)
      qf[sub][ds] = *(const short8*)(qb + rb + ds * 32 + lg * 8);
    iscv[sub] = isc[bh * Tc + qg];
  }

  f32x4 O[2][4];
#pragma unroll
  for (int sub = 0; sub < 2; sub++)
#pragma unroll
    for (int dt = 0; dt < 4; dt++) O[sub][dt] = f32x4{0.f, 0.f, 0.f, 0.f};
  float m[2] = {NINF, NINF}, l[2] = {0.f, 0.f};

  const int rloc = lane >> 3, gsrc = l7 ^ rloc;   // K staging (pre-swizzled source)
  const int kp = tid >> 3, gd = tid & 7;          // V staging: k-pair, d-granule
  const int vswz = kp >> 2;                       // k0>>3
  const int vkoff = (kp & 3) * 4;                 // (k0&7)*2 bytes

  const int ktend = q0 + 127;
  for (int kt = 0; kt <= ktend; kt += 64){
    __syncthreads();
    // --- stage K (global_load_lds, source-swizzled) ---
#pragma unroll
    for (int i = 0; i < 2; i++){
      int chunk = wq * 2 + i;
      const ushort* src = kb + (size_t)(b * Tc + kt + chunk * 8 + rloc) * Dc + h * DHc + gsrc * 8;
      GLDS(src, &Ks[chunk * 512]);
    }
    // --- stage V transposed (reg-staged, swizzled write, lane-rotated for banks) ---
    {
      const ushort* vsrc = vb + (size_t)(b * Tc + kt + kp * 2) * Dc + h * DHc + gd * 8;
      ushort8 va = *(const ushort8*)vsrc;
      ushort8 vc = *(const ushort8*)(vsrc + Dc);
      char* vtb = (char*)Vt;
#pragma unroll
      for (int jj = 0; jj < 8; jj++){
        int j = (jj + l7) & 7;                    // rotate so banks spread within 8-lane groups
        int d = gd * 8 + j;                       // d&7 == j
        uint u = (uint)va[j] | ((uint)vc[j] << 16);
        *(uint*)(vtb + d * 128 + ((vswz ^ j) * 16) + vkoff) = u;
      }
    }
    __syncthreads();

    if (kt <= q0w + 31){                          // wave-active (uniform)
      short8 kf[4][2], vtf[4][2];
#pragma unroll
      for (int t = 0; t < 4; t++)
#pragma unroll
        for (int ds = 0; ds < 2; ds++)
          kf[t][ds] = *(const short8*)&Ks[(t * 16 + la15) * 64 + (((ds * 4 + lg) ^ (la15 & 7)) * 8)];
#pragma unroll
      for (int dt = 0; dt < 4; dt++)
#pragma unroll
        for (int kh = 0; kh < 2; kh++)
          vtf[dt][kh] = *(const short8*)&Vt[(dt * 16 + la15) * 64 + (((kh * 4 + lg) ^ (la15 & 7)) * 8)];

#pragma unroll
      for (int sub = 0; sub < 2; sub++){
        if (kt > q0w + sub * 16 + 15) continue;   // sub-active (uniform)
        // QK^T (swapped): S^T tiles
        f32x4 s[4];
#pragma unroll
        for (int t = 0; t < 4; t++){
          s[t] = f32x4{0.f, 0.f, 0.f, 0.f};
#pragma unroll
          for (int ds = 0; ds < 2; ds++)
            s[t] = __builtin_amdgcn_mfma_f32_16x16x32_bf16(kf[t][ds], qf[sub][ds], s[t], 0, 0, 0);
        }
        // softmax (q = la15; k-values in-lane across 4 tiles x 4 regs)
        const int qg = q0w + sub * 16 + la15;
        const float sc = iscv[sub];
        const bool diag = (kt + 63 > q0w + sub * 16);
        float p[4][4];
        float pm = NINF;
#pragma unroll
        for (int t = 0; t < 4; t++)
#pragma unroll
          for (int r = 0; r < 4; r++){
            float v = s[t][r] * sc;
            if (diag){
              int kpos = kt + t * 16 + lg * 4 + r;
              if (kpos > qg) v = NINF;
            }
            p[t][r] = v;
            pm = fmaxf(pm, v);
          }
        pm = fmaxf(pm, __shfl_xor(pm, 16, 64));
        pm = fmaxf(pm, __shfl_xor(pm, 32, 64));
        float mnew = fmaxf(m[sub], pm);
        float esc = __expf(m[sub] - mnew);
        m[sub] = mnew;
        float rs = 0.f;
#pragma unroll
        for (int t = 0; t < 4; t++)
#pragma unroll
          for (int r = 0; r < 4; r++){
            float e = __expf(p[t][r] - mnew);
            p[t][r] = e; rs += e;
          }
        rs += __shfl_xor(rs, 16, 64);
        rs += __shfl_xor(rs, 32, 64);
        l[sub] = l[sub] * esc + rs;
#pragma unroll
        for (int dt = 0; dt < 4; dt++) O[sub][dt] *= esc;
        // pack P^T pairs (k = tile*16 + lg*4 + {2pr, 2pr+1})
        uint up[4][2];
#pragma unroll
        for (int t = 0; t < 4; t++)
#pragma unroll
          for (int pr = 0; pr < 2; pr++)
            up[t][pr] = (uint)f2b(p[t][2 * pr]) | ((uint)f2b(p[t][2 * pr + 1]) << 16);
        // assemble PV B-operand frags via shfl (src lane lg_s = (lg&1)*2 + (c>>1))
        const int srcb = ((lg & 1) * 2) * 16 + la15;
        const bool hi = (lg >> 1) & 1;            // tile select t = kh*2 + (lg>>1)
#pragma unroll
        for (int kh = 0; kh < 2; kh++){
          union { uint4v w; short8 s8; } pf;
#pragma unroll
          for (int c = 0; c < 4; c++){
            int src = srcb + (c >> 1) * 16;
            uint r1 = (uint)__shfl((int)up[kh * 2 + 0][c & 1], src, 64);
            uint r2 = (uint)__shfl((int)up[kh * 2 + 1][c & 1], src, 64);
            pf.w[c] = hi ? r2 : r1;
          }
#pragma unroll
          for (int dt = 0; dt < 4; dt++)
            O[sub][dt] = __builtin_amdgcn_mfma_f32_16x16x32_bf16(vtf[dt][kh], pf.s8, O[sub][dt], 0, 0, 0);
        }
      }
    }
  }

  // epilogue: normalize, transpose through LDS (per-wave region), coalesced bf16 store
  __syncthreads();
  char* osb = (char*)smem + wq * 4352;            // 32 rows x 136 B
#pragma unroll
  for (int sub = 0; sub < 2; sub++){
    float inv = 1.f / l[sub];
#pragma unroll
    for (int dt = 0; dt < 4; dt++)
#pragma unroll
      for (int pr = 0; pr < 2; pr++){
        uint u = (uint)f2b(O[sub][dt][2 * pr] * inv) | ((uint)f2b(O[sub][dt][2 * pr + 1] * inv) << 16);
        *(uint*)(osb + (sub * 16 + la15) * 136 + (dt * 16 + lg * 4 + pr * 2) * 2) = u;
      }
  }
#pragma unroll
  for (int it = 0; it < 4; it++){
    int ql = it * 8 + (lane >> 3);
    ushort8 v = *(const ushort8*)(osb + ql * 136 + l7 * 16);
    *(ushort8*)(ao + (size_t)(b * Tc + q0 + wq * 32 + ql) * Dc + h * DHc + l7 * 8) = v;
  }
}

// ---------------- host ----------------
extern "C" void kernel_launch(void* const* d_in, const int* in_sizes, int n_in,
                              void* d_out, int out_size, void* d_ws, size_t ws_size,
                              hipStream_t stream){
  (void)in_sizes; (void)n_in; (void)out_size; (void)ws_size;
  const float* x    = (const float*)d_in[0];
  const float* cosa = (const float*)d_in[1];
  const float* sina = (const float*)d_in[2];
  const float* sigma= (const float*)d_in[3];
  // d_in[4] = causal_mask (unused; causality handled analytically)
  const float* ln1g = (const float*)d_in[5];
  const float* ln1b = (const float*)d_in[6];
  const float* wq   = (const float*)d_in[7];
  const float* bq   = (const float*)d_in[8];
  const float* wk   = (const float*)d_in[9];
  const float* bk   = (const float*)d_in[10];
  const float* wv   = (const float*)d_in[11];
  const float* bv   = (const float*)d_in[12];
  const float* wo   = (const float*)d_in[13];
  const float* bo   = (const float*)d_in[14];
  const float* ln2g = (const float*)d_in[15];
  const float* ln2b = (const float*)d_in[16];
  const float* w1   = (const float*)d_in[17];
  const float* b1   = (const float*)d_in[18];
  const float* w2   = (const float*)d_in[19];
  const float* b2   = (const float*)d_in[20];
  float* out = (float*)d_out;

  char* ws = (char*)d_ws;
  constexpr size_t MB = 1024 * 1024;
  ushort* wqT  = (ushort*)(ws +  0 * MB);  // 2MB  (D x D bf16, transposed)
  ushort* wkT  = (ushort*)(ws +  2 * MB);
  ushort* wvT  = (ushort*)(ws +  4 * MB);
  ushort* woT  = (ushort*)(ws +  6 * MB);
  ushort* w1T  = (ushort*)(ws +  8 * MB);  // 8MB  (4D x D)
  ushort* w2T  = (ushort*)(ws + 16 * MB);  // 8MB  (D x 4D)
  ushort* hb   = (ushort*)(ws + 24 * MB);  // 8MB  h (bf16); reused for h2 after attention
  ushort* qbuf = (ushort*)(ws + 32 * MB);  // 8MB; [32..64)MB reused as gelu-out (32MB) in FFN
  ushort* kbuf = (ushort*)(ws + 40 * MB);
  ushort* vbuf = (ushort*)(ws + 48 * MB);
  ushort* aob  = (ushort*)(ws + 56 * MB);
  float*  x2   = (float*)(ws + 64 * MB);   // 16MB
  float*  iscp = (float*)(ws + 80 * MB);   // 256KB
  ushort* g1b  = qbuf;                     // 32MB alias over qbuf/kbuf/vbuf/aob (dead by then)

  // 1. weight transpose + convert
  k_transcvt<<<dim3(Dc / 32, Dc / 32), 256, 0, stream>>>(wq, wqT, Dc, Dc);
  k_transcvt<<<dim3(Dc / 32, Dc / 32), 256, 0, stream>>>(wk, wkT, Dc, Dc);
  k_transcvt<<<dim3(Dc / 32, Dc / 32), 256, 0, stream>>>(wv, wvT, Dc, Dc);
  k_transcvt<<<dim3(Dc / 32, Dc / 32), 256, 0, stream>>>(wo, woT, Dc, Dc);
  k_transcvt<<<dim3(D4c / 32, Dc / 32), 256, 0, stream>>>(w1, w1T, Dc, D4c);
  k_transcvt<<<dim3(Dc / 32, D4c / 32), 256, 0, stream>>>(w2, w2T, D4c, Dc);
  // 2. LN1
  k_ln<<<Rc, 256, 0, stream>>>(x, ln1g, ln1b, hb);
  // 3. QKV projections (bf16 out)
  k_gemm<1, 0, 0><<<dim3(Dc / 128, Rc / 128), 256, 0, stream>>>(hb, wqT, bq, nullptr, qbuf, Rc, Dc, Dc);
  k_gemm<1, 0, 0><<<dim3(Dc / 128, Rc / 128), 256, 0, stream>>>(hb, wkT, bk, nullptr, kbuf, Rc, Dc, Dc);
  k_gemm<1, 0, 0><<<dim3(Dc / 128, Rc / 128), 256, 0, stream>>>(hb, wvT, bv, nullptr, vbuf, Rc, Dc, Dc);
  // 4. RoPE in-place on Q,K
  k_rope<<<(Bc * Tc * Hc * NBc) / 256, 256, 0, stream>>>(qbuf, kbuf, cosa, sina);
  // 5. temperature -> inv scale
  k_iscale<<<(Bc * Tc * Hc) / 256, 256, 0, stream>>>(sigma, iscp);
  // 6. causal attention (MFMA flash)
  k_attn_mfma<<<dim3(Tc / 128, Bc * Hc), 256, 0, stream>>>(qbuf, kbuf, vbuf, iscp, aob);
  // 7. out-proj + residual (f32 out)
  k_gemm<0, 0, 1><<<dim3(Dc / 128, Rc / 128), 256, 0, stream>>>(aob, woT, bo, x, x2, Rc, Dc, Dc);
  // 8. LN2
  k_ln<<<Rc, 256, 0, stream>>>(x2, ln2g, ln2b, hb);
  // 9. FFN1 + exact GELU (bf16 out)
  k_gemm<1, 1, 0><<<dim3(D4c / 128, Rc / 128), 256, 0, stream>>>(hb, w1T, b1, nullptr, g1b, Rc, D4c, Dc);
  // 10. FFN2 + residual -> final output (f32)
  k_gemm<0, 0, 1><<<dim3(Dc / 128, Rc / 128), 256, 0, stream>>>(g1b, w2T, b2, x2, out, Rc, Dc, D4c);
}